// Round 7
// baseline (167.477 us; speedup 1.0000x reference)
//
#include <hip/hip_runtime.h>
#include <math.h>

// N=5000 nodes, E=80000 edges, C=32, H=W=8  -> CHW = 2048 elems/node
#define CCH   32
#define HWPIX 64
#define CHW   2048
#define HT_STRIDE 40   // shorts per pixel-row in LDS (16B-aligned, pad 8)
#define HT_NODE   2600 // 65 rows * 40 shorts (row 64 = zeros)

typedef __attribute__((ext_vector_type(8))) short bf16x8;
typedef __attribute__((ext_vector_type(4))) float f32x4;
typedef unsigned int uint_t;
typedef unsigned short ushort_t;

__device__ __forceinline__ ushort_t f2bf(float f) {  // RNE f32->bf16
    uint_t u = __float_as_uint(f);
    u += 0x7fffu + ((u >> 16) & 1u);
    return (ushort_t)(u >> 16);
}

// tanh-form GELU: x * sigmoid(1.5957691216*(x + 0.044715 x^3)).
// |err vs exact erf-GELU| <= ~0.003 abs — within threshold budget.
__device__ __forceinline__ float fgelu(float x) {
    float x2 = x * x;
    float t = x * fmaf(0.0713548162726f, x2, 1.5957691216f);
    float ez = __expf(-t);
    return x * __builtin_amdgcn_rcpf(1.0f + ez);
}

// ---------------- hist + weight-prep + (last-done-block) scan ----------------
// Blocks [0,nhist): histogram of dst. Block nhist: weight A-frag prep.
// Every block then bumps `done` (ACQ_REL, device scope); the LAST block to
// finish runs the exclusive scan — no co-residency or spin required.
__global__ __launch_bounds__(256) void hist_prep_scan_kernel(
    const int* __restrict__ dst, int* cnt, int ne, int nhist,
    const float* __restrict__ w, ushort_t* __restrict__ wfrag,
    int* __restrict__ offs, int* __restrict__ cursor, int* done, int nn) {
    int b = blockIdx.x;
    int t = threadIdx.x;
    if (b < nhist) {
        int i = b * 256 + t;
        if (i < ne) atomicAdd(&cnt[dst[i]], 1);
    } else {
        // A-frag prep for mfma_f32_16x16x32_bf16:
        // A[m=lane&15][k=(lane>>4)*8+j]; wfrag[(ch*9+tap)*64+lane][j]
        for (int idx = t; idx < 18 * 64; idx += 256) {
            int ch = idx / (9 * 64);
            int rem = idx % (9 * 64);
            int tap = rem / 64;
            int l = rem % 64;
            int co = ch * 16 + (l & 15);
            int g = l >> 4;
            for (int j = 0; j < 8; j++) {
                int ci = g * 8 + j;
                wfrag[(size_t)idx * 8 + j] = f2bf(w[(co * CCH + ci) * 9 + tap]);
            }
        }
    }
    __syncthreads();
    __shared__ int s_old;
    if (t == 0)
        s_old = __hip_atomic_fetch_add(done, 1, __ATOMIC_ACQ_REL,
                                       __HIP_MEMORY_SCOPE_AGENT);
    __syncthreads();
    if (s_old != nhist) return;  // not the last block

    // ---- scan path (256 threads of the last-finishing block) ----
    __shared__ int part[256];
    int per = (nn + 255) >> 8;
    if (per > 32) per = 32;
    int base = t * per;
    int local[32];
    int sum = 0;
    for (int i = 0; i < per; i++) {
        int idx = base + i;
        int v = 0;
        if (idx < nn)
            v = __hip_atomic_load(&cnt[idx], __ATOMIC_RELAXED,
                                  __HIP_MEMORY_SCOPE_AGENT);
        local[i] = sum;
        sum += v;
    }
    part[t] = sum;
    __syncthreads();
    int acc = sum;
    for (int d = 1; d < 256; d <<= 1) {
        int tv = (t >= d) ? part[t - d] : 0;
        __syncthreads();
        acc += tv;
        part[t] = acc;
        __syncthreads();
    }
    int excl = acc - sum;
    for (int i = 0; i < per; i++) {
        int idx = base + i;
        if (idx < nn) {
            int o = excl + local[i];
            offs[idx] = o;
            cursor[idx] = o;
        }
    }
    if (t == 255) offs[nn] = acc;
}

// ---------------- conv (bf16 MFMA) + fused CSR scatter ----------------
__global__ __launch_bounds__(256) void conv_scatter_kernel(
    const float* __restrict__ h, const ushort_t* __restrict__ wfrag,
    ushort_t* __restrict__ convh, int nconv,
    const int* __restrict__ dst, const int* __restrict__ src,
    const float* __restrict__ e, int* cursor, int2* __restrict__ swA, int ne) {
    __shared__ ushort_t Ht[2 * HT_NODE];  // 10400 B
    int b = blockIdx.x;
    int t = threadIdx.x;

    if (b >= nconv) {  // ---- scatter path (no barriers) ----
        int i = (b - nconv) * 256 + t;
        if (i < ne) {
            int p = atomicAdd(&cursor[dst[i]], 1);
            int2 v;
            v.x = src[i];
            v.y = __float_as_int(e[i]);
            swA[p] = v;
        }
        return;
    }

    // ---- conv path ----
    int node0 = b * 2;
    uint_t* Hd = (uint_t*)Ht;
#pragma unroll
    for (int nd = 0; nd < 2; nd++) {
        const float* hn = h + (size_t)(node0 + nd) * CHW;
#pragma unroll
        for (int it = 0; it < 4; it++) {
            int ci2 = it * 4 + (t >> 6);   // ci pair index 0..15
            int p = t & 63;                // pixel
            float a = hn[ci2 * 128 + p];
            float bb = hn[ci2 * 128 + 64 + p];
            uint_t val = (uint_t)f2bf(a) | ((uint_t)f2bf(bb) << 16);
            Hd[nd * (HT_NODE / 2) + p * (HT_STRIDE / 2) + ci2] = val;
        }
    }
    if (t < 40) Hd[0 * (HT_NODE / 2) + 64 * (HT_STRIDE / 2) + (t % 20)] = 0;
    if (t >= 40 && t < 80) Hd[1 * (HT_NODE / 2) + 64 * (HT_STRIDE / 2) + (t - 40) % 20] = 0;
    __syncthreads();

    int l = t & 63;
    int w = __builtin_amdgcn_readfirstlane(t >> 6);
    int nd = w >> 1;
    int ch = w & 1;
    int s = l & 15, g = l >> 4;
    int n = node0 + nd;

    bf16x8 A[9];
#pragma unroll
    for (int tap = 0; tap < 9; tap++)
        A[tap] = ((const bf16x8*)wfrag)[(ch * 9 + tap) * 64 + l];

    f32x4 C[4];
#pragma unroll
    for (int i = 0; i < 4; i++) C[i] = (f32x4){0.f, 0.f, 0.f, 0.f};

    const short* HtS = (const short*)(Ht + nd * HT_NODE);
#pragma unroll
    for (int tau = 0; tau < 4; tau++) {
        int p = tau * 16 + s;
        int y = p >> 3, x = p & 7;
#pragma unroll
        for (int tap = 0; tap < 9; tap++) {
            int dy = tap / 3 - 1, dx = tap % 3 - 1;
            int yy = y + dy, xx = x + dx;
            bool valid = (yy >= 0) & (yy < 8) & (xx >= 0) & (xx < 8);
            int pp = valid ? (yy * 8 + xx) : 64;
            bf16x8 B = *(const bf16x8*)&HtS[pp * HT_STRIDE + g * 8];
            C[tau] = __builtin_amdgcn_mfma_f32_16x16x32_bf16(A[tap], B, C[tau], 0, 0, 0);
        }
    }

    ushort_t* outn = convh + (size_t)n * CHW;
#pragma unroll
    for (int tau = 0; tau < 4; tau++) {
        uint_t lo = (uint_t)f2bf(C[tau][0]) | ((uint_t)f2bf(C[tau][1]) << 16);
        uint_t hi = (uint_t)f2bf(C[tau][2]) | ((uint_t)f2bf(C[tau][3]) << 16);
        uint2 v; v.x = lo; v.y = hi;
        *(uint2*)(outn + (tau * 16 + s) * 32 + ch * 16 + g * 4) = v;
    }
}

// ---------------- gather: EIGHTH-node slices, paired-edge half-waves ----------------
// Block = 4 waves = 4 nodes x 1 eighth. Eighth q = blockIdx & 7 == XCD id under
// the %8 round-robin, so each XCD's L2 holds a 5000*512B = 2.56 MB slice —
// fully L2-resident. Each half-wave (32 lanes) covers one edge: lanes 0-31
// edge j, lanes 32-63 edge j+1 — one dwordx4/lane (16B) per edge-pair.
// 4 uint4 buffers = 8 edges in flight; descriptors prefetched 16 ahead.
// Halves merged at the end with __shfl_xor(.,32). Tail pads duplicate the
// last edge (min/max-idempotent).
__device__ __forceinline__ void red8(float* mn, float* mx, uint4 q, float wg) {
    uint_t u0 = q.x, u1 = q.y, u2 = q.z, u3 = q.w;
    float v;
    v = wg * __uint_as_float(u0 << 16);          mn[0] = fminf(mn[0], v); mx[0] = fmaxf(mx[0], v);
    v = wg * __uint_as_float(u0 & 0xffff0000u);  mn[1] = fminf(mn[1], v); mx[1] = fmaxf(mx[1], v);
    v = wg * __uint_as_float(u1 << 16);          mn[2] = fminf(mn[2], v); mx[2] = fmaxf(mx[2], v);
    v = wg * __uint_as_float(u1 & 0xffff0000u);  mn[3] = fminf(mn[3], v); mx[3] = fmaxf(mx[3], v);
    v = wg * __uint_as_float(u2 << 16);          mn[4] = fminf(mn[4], v); mx[4] = fmaxf(mx[4], v);
    v = wg * __uint_as_float(u2 & 0xffff0000u);  mn[5] = fminf(mn[5], v); mx[5] = fmaxf(mx[5], v);
    v = wg * __uint_as_float(u3 << 16);          mn[6] = fminf(mn[6], v); mx[6] = fmaxf(mx[6], v);
    v = wg * __uint_as_float(u3 & 0xffff0000u);  mn[7] = fminf(mn[7], v); mx[7] = fmaxf(mx[7], v);
}

__global__ __launch_bounds__(256) void gather_max_kernel(
    const ushort_t* __restrict__ convh, const float* __restrict__ bias,
    const int* __restrict__ offs, const int2* __restrict__ swA,
    float* __restrict__ out) {
    int t = threadIdx.x;
    int l = t & 63;
    int w = t >> 6;
    int b = blockIdx.x;
    int q = b & 7;                 // eighth — tied to XCD via blockIdx % 8
    int n = (b >> 3) * 4 + w;      // node
    int beg = offs[n], end = offs[n + 1];
    int last = end - 1;
    int he = l >> 5;               // half-wave selects edge j / j+1

    const char* sbase = (const char*)convh + 512 * q + 16 * (l & 31);

    float mn[8], mx[8];
#pragma unroll
    for (int i = 0; i < 8; i++) { mn[i] = 3.402823466e+38f; mx[i] = -3.402823466e+38f; }

#define IDX(j) (((j) < last) ? (j) : last)
    int2 d0 = swA[IDX(beg + 0 + he)];
    int2 d1 = swA[IDX(beg + 2 + he)];
    int2 d2 = swA[IDX(beg + 4 + he)];
    int2 d3 = swA[IDX(beg + 6 + he)];
    uint4 Q0 = *(const uint4*)(sbase + (size_t)d0.x * 4096);
    uint4 Q1 = *(const uint4*)(sbase + (size_t)d1.x * 4096);
    uint4 Q2 = *(const uint4*)(sbase + (size_t)d2.x * 4096);
    uint4 Q3 = *(const uint4*)(sbase + (size_t)d3.x * 4096);
    float W0 = __int_as_float(d0.y), W1 = __int_as_float(d1.y);
    float W2 = __int_as_float(d2.y), W3 = __int_as_float(d3.y);
    int2 S0 = swA[IDX(beg + 8 + he)];
    int2 S1 = swA[IDX(beg + 10 + he)];
    int2 S2 = swA[IDX(beg + 12 + he)];
    int2 S3 = swA[IDX(beg + 14 + he)];

    for (int j = beg; j < end; j += 8) {
        int2 N0 = swA[IDX(j + 16 + he)];
        int2 N1 = swA[IDX(j + 18 + he)];
        int2 N2 = swA[IDX(j + 20 + he)];
        int2 N3 = swA[IDX(j + 22 + he)];
        red8(mn, mx, Q0, W0);
        Q0 = *(const uint4*)(sbase + (size_t)S0.x * 4096); W0 = __int_as_float(S0.y);
        red8(mn, mx, Q1, W1);
        Q1 = *(const uint4*)(sbase + (size_t)S1.x * 4096); W1 = __int_as_float(S1.y);
        red8(mn, mx, Q2, W2);
        Q2 = *(const uint4*)(sbase + (size_t)S2.x * 4096); W2 = __int_as_float(S2.y);
        red8(mn, mx, Q3, W3);
        Q3 = *(const uint4*)(sbase + (size_t)S3.x * 4096); W3 = __int_as_float(S3.y);
        S0 = N0; S1 = N1; S2 = N2; S3 = N3;
    }
#undef IDX

    // merge the two half-wave edge streams
#pragma unroll
    for (int i = 0; i < 8; i++) {
        mn[i] = fminf(mn[i], __shfl_xor(mn[i], 32));
        mx[i] = fmaxf(mx[i], __shfl_xor(mx[i], 32));
    }

    if (l < 32) {
        // elem (within node) = q*256 + (l&31)*8 + i
        //   pix = q*8 + (l>>2), co = (l&3)*8 + i; out[n][co][pix] fp32
        const float4* b4 = (const float4*)(bias + (l & 3) * 8);
        float4 bLo = b4[0], bHi = b4[1];
        float bb[8] = {bLo.x, bLo.y, bLo.z, bLo.w, bHi.x, bHi.y, bHi.z, bHi.w};
        float* op = out + (size_t)n * CHW + (size_t)(l & 3) * 512 + q * 8 + (l >> 2);
#pragma unroll
        for (int i = 0; i < 8; i++) {
            op[i * 64] = fmaxf(fgelu(mx[i] + bb[i]), fgelu(mn[i] + bb[i]));
        }
    }
}

extern "C" void kernel_launch(void* const* d_in, const int* in_sizes, int n_in,
                              void* d_out, int out_size, void* d_ws, size_t ws_size,
                              hipStream_t stream) {
    const float* h      = (const float*)d_in[0];
    const float* e      = (const float*)d_in[1];
    const float* conv_w = (const float*)d_in[2];
    const float* conv_b = (const float*)d_in[3];
    const int*   src    = (const int*)d_in[4];
    const int*   dst    = (const int*)d_in[5];
    int nn = in_sizes[0] / CHW;  // 5000
    int ne = in_sizes[1];        // 80000

    // ws layout: convh bf16 | wfrag | cnt[nn]+done | offs(+pad) | cursor | swA(int2)
    ushort_t* convh = (ushort_t*)d_ws;
    ushort_t* wfrag = convh + (size_t)nn * CHW;
    int*   cnt    = (int*)(wfrag + 18 * 64 * 8);
    int*   done   = cnt + nn;
    int*   offs   = done + 1;
    int*   cursor = offs + nn + 2;       // +1 pad int keeps swA 8B-aligned
    int2*  swA    = (int2*)(cursor + nn);

    int nhist = (ne + 255) / 256;  // 313
    int nconv = nn / 2;            // 2500

    hipMemsetAsync(cnt, 0, (size_t)(nn + 1) * sizeof(int), stream);
    hist_prep_scan_kernel<<<nhist + 1, 256, 0, stream>>>(
        dst, cnt, ne, nhist, conv_w, wfrag, offs, cursor, done, nn);
    conv_scatter_kernel<<<nconv + nhist, 256, 0, stream>>>(
        h, wfrag, convh, nconv, dst, src, e, cursor, swA, ne);
    gather_max_kernel<<<(nn / 4) * 8, 256, 0, stream>>>(convh, conv_b, offs, swA,
                                                        (float*)d_out);
}

// Round 10
// 166.104 us; speedup vs baseline: 1.0083x; 1.0083x over previous
//
#include <hip/hip_runtime.h>
#include <math.h>

// N=5000 nodes, E=80000 edges, C=32, H=W=8  -> CHW = 2048 elems/node
#define CCH   32
#define HWPIX 64
#define CHW   2048
#define HT_STRIDE 40   // shorts per pixel-row in LDS (16B-aligned, pad 8)
#define HT_NODE   2600 // 65 rows * 40 shorts (row 64 = zeros)

typedef __attribute__((ext_vector_type(8))) _Float16 f16x8;
typedef __attribute__((ext_vector_type(2))) _Float16 f16x2;
typedef __attribute__((ext_vector_type(4))) float f32x4;
typedef unsigned int uint_t;
typedef unsigned short ushort_t;

__device__ __forceinline__ uint_t pkh2(float a, float b) {  // v_cvt_pkrtz_f16_f32
    auto p = __builtin_amdgcn_cvt_pkrtz(a, b);  // __fp16 ext_vector(2)
    return __builtin_bit_cast(uint_t, p);
}

// tanh-form GELU: x * sigmoid(1.5957691216*(x + 0.044715 x^3)).
__device__ __forceinline__ float fgelu(float x) {
    float x2 = x * x;
    float t = x * fmaf(0.0713548162726f, x2, 1.5957691216f);
    float ez = __expf(-t);
    return x * __builtin_amdgcn_rcpf(1.0f + ez);
}

// ---------------- hist + weight-prep + (last-done-block) scan ----------------
__global__ __launch_bounds__(256) void hist_prep_scan_kernel(
    const int* __restrict__ dst, int* cnt, int ne, int nhist,
    const float* __restrict__ w, ushort_t* __restrict__ wfrag,
    int* __restrict__ offs, int* __restrict__ cursor, int* done, int nn) {
    int b = blockIdx.x;
    int t = threadIdx.x;
    if (b < nhist) {
        int i = b * 256 + t;
        if (i < ne) atomicAdd(&cnt[dst[i]], 1);
    } else {
        // A-frag prep for mfma_f32_16x16x32_f16:
        // A[m=lane&15][k=(lane>>4)*8+j]; wfrag[(ch*9+tap)*64+lane][j]
        for (int idx = t; idx < 18 * 64; idx += 256) {
            int ch = idx / (9 * 64);
            int rem = idx % (9 * 64);
            int tap = rem / 64;
            int l = rem % 64;
            int co = ch * 16 + (l & 15);
            int g = l >> 4;
            for (int j = 0; j < 8; j++) {
                int ci = g * 8 + j;
                wfrag[(size_t)idx * 8 + j] =
                    (ushort_t)(pkh2(w[(co * CCH + ci) * 9 + tap], 0.f) & 0xffffu);
            }
        }
    }
    __syncthreads();
    __shared__ int s_old;
    if (t == 0)
        s_old = __hip_atomic_fetch_add(done, 1, __ATOMIC_ACQ_REL,
                                       __HIP_MEMORY_SCOPE_AGENT);
    __syncthreads();
    if (s_old != nhist) return;  // not the last block

    __shared__ int part[256];
    int per = (nn + 255) >> 8;
    if (per > 32) per = 32;
    int base = t * per;
    int local[32];
    int sum = 0;
    for (int i = 0; i < per; i++) {
        int idx = base + i;
        int v = 0;
        if (idx < nn)
            v = __hip_atomic_load(&cnt[idx], __ATOMIC_RELAXED,
                                  __HIP_MEMORY_SCOPE_AGENT);
        local[i] = sum;
        sum += v;
    }
    part[t] = sum;
    __syncthreads();
    int acc = sum;
    for (int d = 1; d < 256; d <<= 1) {
        int tv = (t >= d) ? part[t - d] : 0;
        __syncthreads();
        acc += tv;
        part[t] = acc;
        __syncthreads();
    }
    int excl = acc - sum;
    for (int i = 0; i < per; i++) {
        int idx = base + i;
        if (idx < nn) {
            int o = excl + local[i];
            offs[idx] = o;
            cursor[idx] = o;
        }
    }
    if (t == 255) offs[nn] = acc;
}

// ---------------- conv (f16 MFMA) + fused CSR scatter ----------------
// Scatter writes (src, packed-f16x2 weight) pairs.
__global__ __launch_bounds__(256) void conv_scatter_kernel(
    const float* __restrict__ h, const ushort_t* __restrict__ wfrag,
    ushort_t* __restrict__ convh, int nconv,
    const int* __restrict__ dst, const int* __restrict__ src,
    const float* __restrict__ e, int* cursor, int2* __restrict__ swA, int ne) {
    __shared__ ushort_t Ht[2 * HT_NODE];  // 10400 B
    int b = blockIdx.x;
    int t = threadIdx.x;

    if (b >= nconv) {  // ---- scatter path (no barriers) ----
        int i = (b - nconv) * 256 + t;
        if (i < ne) {
            int p = atomicAdd(&cursor[dst[i]], 1);
            float ev = e[i];
            int2 v;
            v.x = src[i];
            v.y = (int)pkh2(ev, ev);  // packed f16x2 weight
            swA[p] = v;
        }
        return;
    }

    // ---- conv path ----
    int node0 = b * 2;
    uint_t* Hd = (uint_t*)Ht;
#pragma unroll
    for (int nd = 0; nd < 2; nd++) {
        const float* hn = h + (size_t)(node0 + nd) * CHW;
#pragma unroll
        for (int it = 0; it < 4; it++) {
            int ci2 = it * 4 + (t >> 6);   // ci pair index 0..15
            int p = t & 63;                // pixel
            float a = hn[ci2 * 128 + p];
            float bb = hn[ci2 * 128 + 64 + p];
            Hd[nd * (HT_NODE / 2) + p * (HT_STRIDE / 2) + ci2] = pkh2(a, bb);
        }
    }
    if (t < 40) Hd[0 * (HT_NODE / 2) + 64 * (HT_STRIDE / 2) + (t % 20)] = 0;
    if (t >= 40 && t < 80) Hd[1 * (HT_NODE / 2) + 64 * (HT_STRIDE / 2) + (t - 40) % 20] = 0;
    __syncthreads();

    int l = t & 63;
    int w = __builtin_amdgcn_readfirstlane(t >> 6);
    int nd = w >> 1;
    int ch = w & 1;
    int s = l & 15, g = l >> 4;
    int n = node0 + nd;

    f16x8 A[9];
#pragma unroll
    for (int tap = 0; tap < 9; tap++)
        A[tap] = ((const f16x8*)wfrag)[(ch * 9 + tap) * 64 + l];

    f32x4 C[4];
#pragma unroll
    for (int i = 0; i < 4; i++) C[i] = (f32x4){0.f, 0.f, 0.f, 0.f};

    const short* HtS = (const short*)(Ht + nd * HT_NODE);
#pragma unroll
    for (int tau = 0; tau < 4; tau++) {
        int p = tau * 16 + s;
        int y = p >> 3, x = p & 7;
#pragma unroll
        for (int tap = 0; tap < 9; tap++) {
            int dy = tap / 3 - 1, dx = tap % 3 - 1;
            int yy = y + dy, xx = x + dx;
            bool valid = (yy >= 0) & (yy < 8) & (xx >= 0) & (xx < 8);
            int pp = valid ? (yy * 8 + xx) : 64;
            f16x8 B = *(const f16x8*)&HtS[pp * HT_STRIDE + g * 8];
            C[tau] = __builtin_amdgcn_mfma_f32_16x16x32_f16(A[tap], B, C[tau], 0, 0, 0);
        }
    }

    ushort_t* outn = convh + (size_t)n * CHW;
#pragma unroll
    for (int tau = 0; tau < 4; tau++) {
        uint2 v;
        v.x = pkh2(C[tau][0], C[tau][1]);
        v.y = pkh2(C[tau][2], C[tau][3]);
        *(uint2*)(outn + (tau * 16 + s) * 32 + ch * 16 + g * 4) = v;
    }
}

// ---------------- gather: eighth-node slices, paired-edge half-waves, packed f16 ----------------
// Block = 4 waves = 4 nodes x 1 eighth; q = blockIdx & 7 == XCD under %8 mapping,
// each XCD L2 caches a 2.56 MB slice. Half-wave handles one edge (lanes 0-31
// edge j, 32-63 edge j+1); one uint4 = 8 f16 elems; reduction in packed f16
// via native vector ops (v_pk_mul/min/max_f16): 12 VALU per uint4. Halves
// merged with __shfl_xor(.,32). Tail pads duplicate last edge (idempotent).
__device__ __forceinline__ void red4(f16x2* mn, f16x2* mx, uint4 qv, f16x2 wg2) {
    f16x2 a0 = __builtin_bit_cast(f16x2, qv.x) * wg2;
    f16x2 a1 = __builtin_bit_cast(f16x2, qv.y) * wg2;
    f16x2 a2 = __builtin_bit_cast(f16x2, qv.z) * wg2;
    f16x2 a3 = __builtin_bit_cast(f16x2, qv.w) * wg2;
    mn[0] = __builtin_elementwise_min(mn[0], a0);
    mx[0] = __builtin_elementwise_max(mx[0], a0);
    mn[1] = __builtin_elementwise_min(mn[1], a1);
    mx[1] = __builtin_elementwise_max(mx[1], a1);
    mn[2] = __builtin_elementwise_min(mn[2], a2);
    mx[2] = __builtin_elementwise_max(mx[2], a2);
    mn[3] = __builtin_elementwise_min(mn[3], a3);
    mx[3] = __builtin_elementwise_max(mx[3], a3);
}

__global__ __launch_bounds__(256) void gather_max_kernel(
    const ushort_t* __restrict__ convh, const float* __restrict__ bias,
    const int* __restrict__ offs, const int2* __restrict__ swA,
    float* __restrict__ out) {
    int t = threadIdx.x;
    int l = t & 63;
    int w = t >> 6;
    int b = blockIdx.x;
    int q = b & 7;                 // eighth — tied to XCD via blockIdx % 8
    int n = (b >> 3) * 4 + w;      // node
    int beg = offs[n], end = offs[n + 1];
    int last = end - 1;
    int he = l >> 5;               // half-wave selects edge j / j+1

    const char* sbase = (const char*)convh + 512 * q + 16 * (l & 31);

    const uint_t PI = 0x7C007C00u, NI = 0xFC00FC00u;  // +inf/-inf f16x2
    f16x2 mn2[4], mx2[4];
#pragma unroll
    for (int i = 0; i < 4; i++) {
        mn2[i] = __builtin_bit_cast(f16x2, PI);
        mx2[i] = __builtin_bit_cast(f16x2, NI);
    }

#define IDX(j) (((j) < last) ? (j) : last)
    int2 d0 = swA[IDX(beg + 0 + he)];
    int2 d1 = swA[IDX(beg + 2 + he)];
    int2 d2 = swA[IDX(beg + 4 + he)];
    int2 d3 = swA[IDX(beg + 6 + he)];
    uint4 Q0 = *(const uint4*)(sbase + (size_t)d0.x * 4096);
    uint4 Q1 = *(const uint4*)(sbase + (size_t)d1.x * 4096);
    uint4 Q2 = *(const uint4*)(sbase + (size_t)d2.x * 4096);
    uint4 Q3 = *(const uint4*)(sbase + (size_t)d3.x * 4096);
    f16x2 W0 = __builtin_bit_cast(f16x2, d0.y);
    f16x2 W1 = __builtin_bit_cast(f16x2, d1.y);
    f16x2 W2 = __builtin_bit_cast(f16x2, d2.y);
    f16x2 W3 = __builtin_bit_cast(f16x2, d3.y);
    int2 S0 = swA[IDX(beg + 8 + he)];
    int2 S1 = swA[IDX(beg + 10 + he)];
    int2 S2 = swA[IDX(beg + 12 + he)];
    int2 S3 = swA[IDX(beg + 14 + he)];

    for (int j = beg; j < end; j += 8) {
        int2 N0 = swA[IDX(j + 16 + he)];
        int2 N1 = swA[IDX(j + 18 + he)];
        int2 N2 = swA[IDX(j + 20 + he)];
        int2 N3 = swA[IDX(j + 22 + he)];
        red4(mn2, mx2, Q0, W0);
        Q0 = *(const uint4*)(sbase + (size_t)S0.x * 4096);
        W0 = __builtin_bit_cast(f16x2, S0.y);
        red4(mn2, mx2, Q1, W1);
        Q1 = *(const uint4*)(sbase + (size_t)S1.x * 4096);
        W1 = __builtin_bit_cast(f16x2, S1.y);
        red4(mn2, mx2, Q2, W2);
        Q2 = *(const uint4*)(sbase + (size_t)S2.x * 4096);
        W2 = __builtin_bit_cast(f16x2, S2.y);
        red4(mn2, mx2, Q3, W3);
        Q3 = *(const uint4*)(sbase + (size_t)S3.x * 4096);
        W3 = __builtin_bit_cast(f16x2, S3.y);
        S0 = N0; S1 = N1; S2 = N2; S3 = N3;
    }
#undef IDX

    // merge the two half-wave edge streams (packed)
#pragma unroll
    for (int i = 0; i < 4; i++) {
        uint_t mo = __shfl_xor(__builtin_bit_cast(uint_t, mn2[i]), 32);
        mn2[i] = __builtin_elementwise_min(mn2[i], __builtin_bit_cast(f16x2, mo));
        uint_t xo = __shfl_xor(__builtin_bit_cast(uint_t, mx2[i]), 32);
        mx2[i] = __builtin_elementwise_max(mx2[i], __builtin_bit_cast(f16x2, xo));
    }

    if (l < 32) {
        // elem (within node) = q*256 + l*8 + i; pix = q*8 + (l>>2),
        // co = (l&3)*8 + i; out[n][co][pix] fp32
        const float4* b4 = (const float4*)(bias + (l & 3) * 8);
        float4 bLo = b4[0], bHi = b4[1];
        float bb[8] = {bLo.x, bLo.y, bLo.z, bLo.w, bHi.x, bHi.y, bHi.z, bHi.w};
        float mnf[8], mxf[8];
#pragma unroll
        for (int p = 0; p < 4; p++) {
            mnf[2 * p]     = (float)mn2[p][0];
            mnf[2 * p + 1] = (float)mn2[p][1];
            mxf[2 * p]     = (float)mx2[p][0];
            mxf[2 * p + 1] = (float)mx2[p][1];
        }
        float* op = out + (size_t)n * CHW + (size_t)(l & 3) * 512 + q * 8 + (l >> 2);
#pragma unroll
        for (int i = 0; i < 8; i++) {
            op[i * 64] = fmaxf(fgelu(mxf[i] + bb[i]), fgelu(mnf[i] + bb[i]));
        }
    }
}

extern "C" void kernel_launch(void* const* d_in, const int* in_sizes, int n_in,
                              void* d_out, int out_size, void* d_ws, size_t ws_size,
                              hipStream_t stream) {
    const float* h      = (const float*)d_in[0];
    const float* e      = (const float*)d_in[1];
    const float* conv_w = (const float*)d_in[2];
    const float* conv_b = (const float*)d_in[3];
    const int*   src    = (const int*)d_in[4];
    const int*   dst    = (const int*)d_in[5];
    int nn = in_sizes[0] / CHW;  // 5000
    int ne = in_sizes[1];        // 80000

    // ws layout: convh f16 | wfrag | cnt[nn]+done | offs(+pad) | cursor | swA(int2)
    ushort_t* convh = (ushort_t*)d_ws;
    ushort_t* wfrag = convh + (size_t)nn * CHW;
    int*   cnt    = (int*)(wfrag + 18 * 64 * 8);
    int*   done   = cnt + nn;
    int*   offs   = done + 1;
    int*   cursor = offs + nn + 2;       // +1 pad int keeps swA 8B-aligned
    int2*  swA    = (int2*)(cursor + nn);

    int nhist = (ne + 255) / 256;  // 313
    int nconv = nn / 2;            // 2500

    (void)hipMemsetAsync(cnt, 0, (size_t)(nn + 1) * sizeof(int), stream);
    hist_prep_scan_kernel<<<nhist + 1, 256, 0, stream>>>(
        dst, cnt, ne, nhist, conv_w, wfrag, offs, cursor, done, nn);
    conv_scatter_kernel<<<nconv + nhist, 256, 0, stream>>>(
        h, wfrag, convh, nconv, dst, src, e, cursor, swA, ne);
    gather_max_kernel<<<(nn / 4) * 8, 256, 0, stream>>>(convh, conv_b, offs, swA,
                                                        (float*)d_out);
}